// Round 2
// baseline (344.873 us; speedup 1.0000x reference)
//
#include <hip/hip_runtime.h>

#define B_   64
#define L_   1024
#define D_   64
#define QT   16            // q-rows per block
#define SW   1040          // S stride (f16): 2080 B/row, 16B-aligned
#define KSW  72            // K-stage stride (f16): 144 B/row
#define VSW  72            // V-stage stride (f16): 144 B/row

typedef _Float16 f16;
typedef __attribute__((ext_vector_type(8))) _Float16 f16x8;
typedef __attribute__((ext_vector_type(4))) float f32x4;

__global__ __launch_bounds__(256, 2)
void sdpa_kernel(const float* __restrict__ q, const float* __restrict__ kk,
                 const float* __restrict__ v, const unsigned char* __restrict__ mask,
                 float* __restrict__ out, float* __restrict__ attn)
{
    __shared__ f16 S[QT * SW];           // 33280 B: masked scores -> normalized p
    __shared__ f16 Kst[2 * 64 * KSW];    // 18432 B: K chunk hi | lo
    __shared__ f16 Vst[64 * VSW];        // 9216 B: V chunk transposed
    __shared__ float wmax[4][QT];        // per-wave row maxima

    const int tid = threadIdx.x;
    const int l = tid & 63;
    const int w = tid >> 6;
    const int wk = w;                    // wave's k/n sub-tile (0..3)
    const int bid = blockIdx.x;
    const int b = bid >> 6;              // 64 q-tiles per batch
    const int qt = bid & 63;
    const int qbase = b * L_ + qt * QT;  // global q-row base

    // ---- runtime mask element-width detection (deterministic) ----
    unsigned det = 0;
    {
        const unsigned* mw = (const unsigned*)mask;
        #pragma unroll
        for (int i = 0; i < 32; ++i) det |= mw[i];
    }
    const bool elem4 = (det <= 1u) || (det == 0x3F800000u);

    // ---- Q fragments: f16 hi/lo split, rows l&15, d-halves s ----
    f16x8 aqh[2], aql[2];
    {
        const float* qp = q + (size_t)(qbase + (l & 15)) * D_;
        #pragma unroll
        for (int s = 0; s < 2; ++s) {
            const float* p = qp + s * 32 + (l >> 4) * 8;
            float4 f0 = *(const float4*)p;
            float4 f1 = *(const float4*)(p + 4);
            float fv[8] = {f0.x, f0.y, f0.z, f0.w, f1.x, f1.y, f1.z, f1.w};
            #pragma unroll
            for (int j = 0; j < 8; ++j) {
                f16 h = (f16)fv[j];
                aqh[s][j] = h;
                aql[s][j] = (f16)(fv[j] - (float)h);
            }
        }
    }

    const int kr = tid >> 2, kd0 = (tid & 3) * 16;   // K/V staging role

    // ---- prologue: stage K chunk 0 ----
    {
        const float* kp = kk + (size_t)(b * L_ + kr) * D_ + kd0;
        float4 g0 = *(const float4*)kp;
        float4 g1 = *(const float4*)(kp + 4);
        float4 g2 = *(const float4*)(kp + 8);
        float4 g3 = *(const float4*)(kp + 12);
        float fa[8] = {g0.x, g0.y, g0.z, g0.w, g1.x, g1.y, g1.z, g1.w};
        float fb[8] = {g2.x, g2.y, g2.z, g2.w, g3.x, g3.y, g3.z, g3.w};
        f16x8 h0, l0, h1, l1;
        #pragma unroll
        for (int j = 0; j < 8; ++j) {
            f16 h = (f16)fa[j]; h0[j] = h; l0[j] = (f16)(fa[j] - (float)h);
            h = (f16)fb[j];     h1[j] = h; l1[j] = (f16)(fb[j] - (float)h);
        }
        *(f16x8*)&Kst[kr * KSW + kd0]     = h0;
        *(f16x8*)&Kst[kr * KSW + kd0 + 8] = h1;
        *(f16x8*)&Kst[64 * KSW + kr * KSW + kd0]     = l0;
        *(f16x8*)&Kst[64 * KSW + kr * KSW + kd0 + 8] = l1;
    }
    __syncthreads();

    // ---- phase A: 16 chunks of 64 k-cols; masked scores -> S (f16) ----
    float vmax[4] = {-INFINITY, -INFINITY, -INFINITY, -INFINITY};
    for (int ck = 0; ck < 16; ++ck) {
        // 1. issue next K chunk loads (latency hides under MFMAs)
        float4 g0, g1, g2, g3;
        if (ck < 15) {
            const float* kp = kk + (size_t)(b * L_ + (ck + 1) * 64 + kr) * D_ + kd0;
            g0 = *(const float4*)kp;
            g1 = *(const float4*)(kp + 4);
            g2 = *(const float4*)(kp + 8);
            g3 = *(const float4*)(kp + 12);
        }
        // 2. mask loads for current chunk (consumed after MFMAs)
        int mv[4];
        const size_t mbase = (size_t)(qbase + (l >> 4) * 4) * L_
                           + (size_t)ck * 64 + wk * 16 + (l & 15);
        if (elem4) {
            #pragma unroll
            for (int r2 = 0; r2 < 4; ++r2) mv[r2] = ((const int*)mask)[mbase + (size_t)r2 * L_];
        } else {
            #pragma unroll
            for (int r2 = 0; r2 < 4; ++r2) mv[r2] = mask[mbase + (size_t)r2 * L_];
        }
        // 3. QK^T for this wave's 16 k-cols (hi/lo: qh*kh + ql*kh + qh*kl)
        f32x4 acc = {0.f, 0.f, 0.f, 0.f};
        #pragma unroll
        for (int s = 0; s < 2; ++s) {
            const int ko = (wk * 16 + (l & 15)) * KSW + s * 32 + (l >> 4) * 8;
            f16x8 bh = *(const f16x8*)&Kst[ko];
            f16x8 bl = *(const f16x8*)&Kst[64 * KSW + ko];
            acc = __builtin_amdgcn_mfma_f32_16x16x32_f16(aqh[s], bh, acc, 0, 0, 0);
            acc = __builtin_amdgcn_mfma_f32_16x16x32_f16(aql[s], bh, acc, 0, 0, 0);
            acc = __builtin_amdgcn_mfma_f32_16x16x32_f16(aqh[s], bl, acc, 0, 0, 0);
        }
        // 4. mask + scale + store f16 scores + running row max
        const int scol = ck * 64 + wk * 16 + (l & 15);
        #pragma unroll
        for (int r2 = 0; r2 < 4; ++r2) {
            float sv = mv[r2] ? -INFINITY : acc[r2] * 0.125f;
            S[((l >> 4) * 4 + r2) * SW + scol] = (f16)sv;
            vmax[r2] = fmaxf(vmax[r2], sv);
        }
        __syncthreads();                    // all reads of Kst(ck) done
        // 5. write next chunk into Kst
        if (ck < 15) {
            float fa[8] = {g0.x, g0.y, g0.z, g0.w, g1.x, g1.y, g1.z, g1.w};
            float fb[8] = {g2.x, g2.y, g2.z, g2.w, g3.x, g3.y, g3.z, g3.w};
            f16x8 h0, l0, h1, l1;
            #pragma unroll
            for (int j = 0; j < 8; ++j) {
                f16 h = (f16)fa[j]; h0[j] = h; l0[j] = (f16)(fa[j] - (float)h);
                h = (f16)fb[j];     h1[j] = h; l1[j] = (f16)(fb[j] - (float)h);
            }
            *(f16x8*)&Kst[kr * KSW + kd0]     = h0;
            *(f16x8*)&Kst[kr * KSW + kd0 + 8] = h1;
            *(f16x8*)&Kst[64 * KSW + kr * KSW + kd0]     = l0;
            *(f16x8*)&Kst[64 * KSW + kr * KSW + kd0 + 8] = l1;
            __syncthreads();                // Kst(ck+1) visible
        }
    }

    // ---- row-max reduce: 16 lanes (cols) via shfl, 4 waves via LDS ----
    #pragma unroll
    for (int r2 = 0; r2 < 4; ++r2) {
        #pragma unroll
        for (int off = 1; off < 16; off <<= 1)
            vmax[r2] = fmaxf(vmax[r2], __shfl_xor(vmax[r2], off));
    }
    if ((l & 15) == 0) {
        #pragma unroll
        for (int r2 = 0; r2 < 4; ++r2) wmax[w][(l >> 4) * 4 + r2] = vmax[r2];
    }
    __syncthreads();

    // ---- phase B: softmax + attn write + p back to S (one sweep) ----
    {
        const int row = tid >> 4;            // 0..15
        const int cg = tid & 15;             // 16 lanes own a full row
        const float m = fmaxf(fmaxf(wmax[0][row], wmax[1][row]),
                              fmaxf(wmax[2][row], wmax[3][row]));
        float er[64];
        float sum = 0.f;
        #pragma unroll
        for (int c = 0; c < 8; ++c) {
            f16x8 sv = *(const f16x8*)&S[row * SW + (cg + 16 * c) * 8];
            #pragma unroll
            for (int j = 0; j < 8; ++j) {
                float e = __expf((float)sv[j] - m);
                er[c * 8 + j] = e;
                sum += e;
            }
        }
        #pragma unroll
        for (int off = 1; off < 16; off <<= 1) sum += __shfl_xor(sum, off);
        const float inv = 1.0f / sum;
        float* ap = attn + (size_t)(qbase + row) * L_;
        #pragma unroll
        for (int c = 0; c < 8; ++c) {
            float4 p0, p1;
            f16x8 pv;
            p0.x = er[c * 8 + 0] * inv; p0.y = er[c * 8 + 1] * inv;
            p0.z = er[c * 8 + 2] * inv; p0.w = er[c * 8 + 3] * inv;
            p1.x = er[c * 8 + 4] * inv; p1.y = er[c * 8 + 5] * inv;
            p1.z = er[c * 8 + 6] * inv; p1.w = er[c * 8 + 7] * inv;
            pv[0] = (f16)p0.x; pv[1] = (f16)p0.y; pv[2] = (f16)p0.z; pv[3] = (f16)p0.w;
            pv[4] = (f16)p1.x; pv[5] = (f16)p1.y; pv[6] = (f16)p1.z; pv[7] = (f16)p1.w;
            *(float4*)(ap + (cg + 16 * c) * 8)     = p0;
            *(float4*)(ap + (cg + 16 * c) * 8 + 4) = p1;
            *(f16x8*)&S[row * SW + (cg + 16 * c) * 8] = pv;
        }
    }
    __syncthreads();

    // ---- phase C: O = P V via MFMA, V chunks of 64 rows transposed ----
    f32x4 acc2 = {0.f, 0.f, 0.f, 0.f};
    // prologue: stage V chunk 0
    {
        const float* vp = v + (size_t)(b * L_ + kr) * D_ + kd0;
        float4 g0 = *(const float4*)vp;
        float4 g1 = *(const float4*)(vp + 4);
        float4 g2 = *(const float4*)(vp + 8);
        float4 g3 = *(const float4*)(vp + 12);
        float fa[8] = {g0.x, g0.y, g0.z, g0.w, g1.x, g1.y, g1.z, g1.w};
        float fb[8] = {g2.x, g2.y, g2.z, g2.w, g3.x, g3.y, g3.z, g3.w};
        #pragma unroll
        for (int j = 0; j < 8; ++j) {
            Vst[(kd0 + j) * VSW + kr]     = (f16)fa[j];
            Vst[(kd0 + 8 + j) * VSW + kr] = (f16)fb[j];
        }
    }
    __syncthreads();
    for (int vt = 0; vt < 16; ++vt) {
        float4 g0, g1, g2, g3;
        if (vt < 15) {
            const float* vp = v + (size_t)(b * L_ + (vt + 1) * 64 + kr) * D_ + kd0;
            g0 = *(const float4*)vp;
            g1 = *(const float4*)(vp + 4);
            g2 = *(const float4*)(vp + 8);
            g3 = *(const float4*)(vp + 12);
        }
        #pragma unroll
        for (int kh = 0; kh < 2; ++kh) {
            f16x8 pa = *(const f16x8*)&S[(l & 15) * SW + vt * 64 + kh * 32 + (l >> 4) * 8];
            f16x8 bv = *(const f16x8*)&Vst[(wk * 16 + (l & 15)) * VSW + kh * 32 + (l >> 4) * 8];
            acc2 = __builtin_amdgcn_mfma_f32_16x16x32_f16(pa, bv, acc2, 0, 0, 0);
        }
        __syncthreads();                    // reads of Vst(vt) done
        if (vt < 15) {
            float fa[8] = {g0.x, g0.y, g0.z, g0.w, g1.x, g1.y, g1.z, g1.w};
            float fb[8] = {g2.x, g2.y, g2.z, g2.w, g3.x, g3.y, g3.z, g3.w};
            #pragma unroll
            for (int j = 0; j < 8; ++j) {
                Vst[(kd0 + j) * VSW + kr]     = (f16)fa[j];
                Vst[(kd0 + 8 + j) * VSW + kr] = (f16)fb[j];
            }
            __syncthreads();                // Vst(vt+1) visible
        }
    }

    // ---- epilogue: out (already normalized) ----
    #pragma unroll
    for (int r2 = 0; r2 < 4; ++r2) {
        out[(size_t)(qbase + (l >> 4) * 4 + r2) * D_ + wk * 16 + (l & 15)] = acc2[r2];
    }
}

extern "C" void kernel_launch(void* const* d_in, const int* in_sizes, int n_in,
                              void* d_out, int out_size, void* d_ws, size_t ws_size,
                              hipStream_t stream) {
    const float* q = (const float*)d_in[0];
    const float* k = (const float*)d_in[1];
    const float* v = (const float*)d_in[2];
    const unsigned char* mask = (const unsigned char*)d_in[3];
    float* out = (float*)d_out;
    float* attn = out + (size_t)B_ * L_ * D_;
    dim3 grid(B_ * (L_ / QT));
    sdpa_kernel<<<grid, 256, 0, stream>>>(q, k, v, mask, out, attn);
}

// Round 3
// 302.915 us; speedup vs baseline: 1.1385x; 1.1385x over previous
//
#include <hip/hip_runtime.h>

#define B_ 64
#define L_ 1024
#define D_ 64
#define QT 16

typedef _Float16 f16;
typedef __attribute__((ext_vector_type(8))) _Float16 f16x8;
typedef __attribute__((ext_vector_type(4))) float f32x4;

// S is [16 rows][1024 cols] f16, stored in 8-element (16 B) groups with the
// group index XOR-swizzled by (row & 7) to spread banks (row stride 2 KB = 0 mod 32 banks).
__device__ __forceinline__ int sidx(int row, int col) {
    return row * 1024 + ((((col >> 3) ^ (row & 7)) << 3) | (col & 7));
}

__global__ __launch_bounds__(256, 4)
void sdpa_kernel(const float* __restrict__ q, const float* __restrict__ kk,
                 const float* __restrict__ v, const unsigned char* __restrict__ mask,
                 float* __restrict__ out, float* __restrict__ attn)
{
    __shared__ f16 S[QT * 1024];        // 32 KB: scores -> unnormalized e
    __shared__ float wmax[4][QT];
    __shared__ float wsum[QT];

    const int tid = threadIdx.x;
    const int l = tid & 63, w = tid >> 6;
    const int lr = l & 15, lg = l >> 4;
    const int bid = blockIdx.x;
    const int b = bid >> 6, qt = bid & 63;
    const int qbase = b * L_ + qt * QT;

    // ---- runtime mask element-width detection (deterministic) ----
    unsigned det = 0;
    {
        const unsigned* mw = (const unsigned*)mask;
        #pragma unroll
        for (int i = 0; i < 32; ++i) det |= mw[i];
    }
    const bool elem4 = (det <= 1u) || (det == 0x3F800000u);

    // ---- Q fragments: f16 hi/lo split ----
    f16x8 aqh[2], aql[2];
    {
        const float* qp = q + (size_t)(qbase + lr) * D_;
        #pragma unroll
        for (int s = 0; s < 2; ++s) {
            float4 f0 = *(const float4*)(qp + s * 32 + lg * 8);
            float4 f1 = *(const float4*)(qp + s * 32 + lg * 8 + 4);
            float fv[8] = {f0.x, f0.y, f0.z, f0.w, f1.x, f1.y, f1.z, f1.w};
            #pragma unroll
            for (int j = 0; j < 8; ++j) {
                f16 h = (f16)fv[j];
                aqh[s][j] = h;
                aql[s][j] = (f16)(fv[j] - (float)h);
            }
        }
    }

    // ---- phase A: barrier-free QK^T; B-frag direct from global ----
    // bh/bl[s][j] = K[ck*64 + w*16 + lr][s*32 + lg*8 + j]  (hi/lo f16)
    float vmax[4] = {-INFINITY, -INFINITY, -INFINITY, -INFINITY};
    const float* kb = kk + (size_t)(b * L_ + w * 16 + lr) * D_ + lg * 8;
    const size_t mrowbase = (size_t)(qbase + lg * 4) * L_ + w * 16 + lr;

    float4 kc[4];
    kc[0] = *(const float4*)kb;
    kc[1] = *(const float4*)(kb + 4);
    kc[2] = *(const float4*)(kb + 32);
    kc[3] = *(const float4*)(kb + 36);
    int mcur[4], mnxt[4];
    #pragma unroll
    for (int r2 = 0; r2 < 4; ++r2) {
        if (elem4) {
            mcur[r2] = ((const int*)mask)[mrowbase + (size_t)r2 * L_];
            mnxt[r2] = ((const int*)mask)[mrowbase + (size_t)r2 * L_ + 64];
        } else {
            mcur[r2] = mask[mrowbase + (size_t)r2 * L_];
            mnxt[r2] = mask[mrowbase + (size_t)r2 * L_ + 64];
        }
    }

    for (int ck = 0; ck < 16; ++ck) {
        float4 kn[4];
        if (ck < 15) {
            const float* kp = kb + (size_t)(ck + 1) * 64 * D_;
            kn[0] = *(const float4*)kp;
            kn[1] = *(const float4*)(kp + 4);
            kn[2] = *(const float4*)(kp + 32);
            kn[3] = *(const float4*)(kp + 36);
        }
        int mfut[4];
        if (ck < 14) {
            const size_t mo = mrowbase + (size_t)(ck + 2) * 64;
            if (elem4) {
                #pragma unroll
                for (int r2 = 0; r2 < 4; ++r2) mfut[r2] = ((const int*)mask)[mo + (size_t)r2 * L_];
            } else {
                #pragma unroll
                for (int r2 = 0; r2 < 4; ++r2) mfut[r2] = mask[mo + (size_t)r2 * L_];
            }
        }
        // convert current K regs to hi/lo frags
        f16x8 bh[2], bl[2];
        #pragma unroll
        for (int s = 0; s < 2; ++s) {
            float fv[8] = {kc[2*s].x, kc[2*s].y, kc[2*s].z, kc[2*s].w,
                           kc[2*s+1].x, kc[2*s+1].y, kc[2*s+1].z, kc[2*s+1].w};
            #pragma unroll
            for (int j = 0; j < 8; ++j) {
                f16 h = (f16)fv[j];
                bh[s][j] = h;
                bl[s][j] = (f16)(fv[j] - (float)h);
            }
        }
        f32x4 acc = {0.f, 0.f, 0.f, 0.f};
        #pragma unroll
        for (int s = 0; s < 2; ++s) {
            acc = __builtin_amdgcn_mfma_f32_16x16x32_f16(aqh[s], bh[s], acc, 0, 0, 0);
            acc = __builtin_amdgcn_mfma_f32_16x16x32_f16(aql[s], bh[s], acc, 0, 0, 0);
            acc = __builtin_amdgcn_mfma_f32_16x16x32_f16(aqh[s], bl[s], acc, 0, 0, 0);
        }
        const int scol = ck * 64 + w * 16 + lr;
        #pragma unroll
        for (int r2 = 0; r2 < 4; ++r2) {
            float sv = mcur[r2] ? -INFINITY : acc[r2] * 0.125f;
            S[sidx(lg * 4 + r2, scol)] = (f16)sv;
            vmax[r2] = fmaxf(vmax[r2], sv);
        }
        #pragma unroll
        for (int r2 = 0; r2 < 4; ++r2) { mcur[r2] = mnxt[r2]; }
        if (ck < 14) {
            #pragma unroll
            for (int r2 = 0; r2 < 4; ++r2) { mnxt[r2] = mfut[r2]; }
        }
        if (ck < 15) {
            #pragma unroll
            for (int j = 0; j < 4; ++j) kc[j] = kn[j];
        }
    }
    // row-max: reduce across the 16 lanes that share a row-quad
    #pragma unroll
    for (int r2 = 0; r2 < 4; ++r2) {
        #pragma unroll
        for (int off = 1; off < 16; off <<= 1)
            vmax[r2] = fmaxf(vmax[r2], __shfl_xor(vmax[r2], off));
    }
    if (lr == 0) {
        #pragma unroll
        for (int r2 = 0; r2 < 4; ++r2) wmax[w][lg * 4 + r2] = vmax[r2];
    }
    __syncthreads();

    // ---- phase B: softmax; e (unnormalized) back to S; attn = e/sum ----
    {
        const int row = tid >> 4, cg = tid & 15;
        const float m = fmaxf(fmaxf(wmax[0][row], wmax[1][row]),
                              fmaxf(wmax[2][row], wmax[3][row]));
        float sum = 0.f;
        #pragma unroll
        for (int c = 0; c < 8; ++c) {
            f16* sp = &S[row * 1024 + ((((cg + 16 * c)) ^ (row & 7)) << 3)];
            f16x8 sv = *(const f16x8*)sp;
            f16x8 ev;
            #pragma unroll
            for (int j = 0; j < 8; ++j) {
                float e = __expf((float)sv[j] - m);
                ev[j] = (f16)e;
                sum += e;
            }
            *(f16x8*)sp = ev;
        }
        #pragma unroll
        for (int off = 1; off < 16; off <<= 1) sum += __shfl_xor(sum, off);
        if (cg == 0) wsum[row] = sum;
        __syncthreads();

        const float inv = 1.0f / wsum[row];
        float* ap = attn + (size_t)(qbase + row) * L_;
        #pragma unroll
        for (int c = 0; c < 8; ++c) {
            f16x8 ev = *(const f16x8*)&S[row * 1024 + (((cg + 16 * c) ^ (row & 7)) << 3)];
            float4 p0, p1;
            p0.x = (float)ev[0] * inv; p0.y = (float)ev[1] * inv;
            p0.z = (float)ev[2] * inv; p0.w = (float)ev[3] * inv;
            p1.x = (float)ev[4] * inv; p1.y = (float)ev[5] * inv;
            p1.z = (float)ev[6] * inv; p1.w = (float)ev[7] * inv;
            *(float4*)(ap + (cg + 16 * c) * 8)     = p0;
            *(float4*)(ap + (cg + 16 * c) * 8 + 4) = p1;
        }
    }

    // ---- phase C: barrier-free PV; B-frag direct from global ----
    // bv[j] = V[t*32 + lg*8 + j][w*16 + lr]; A-frag = e rows from S.
    f32x4 acc2 = {0.f, 0.f, 0.f, 0.f};
    const float* vb = v + (size_t)(b * L_) * D_ + w * 16 + lr;
    float vcA[8], vcB[8];
    #pragma unroll
    for (int j = 0; j < 8; ++j) {
        vcA[j] = vb[(size_t)(lg * 8 + j) * D_];
        vcB[j] = vb[(size_t)(32 + lg * 8 + j) * D_];
    }
    for (int tt = 0; tt < 16; ++tt) {
        // even step t = 2*tt (data in vcA)
        {
            f16x8 pa = *(const f16x8*)&S[lr * 1024 + ((((2 * tt) * 4 + lg) ^ (lr & 7)) << 3)];
            f16x8 bv;
            #pragma unroll
            for (int j = 0; j < 8; ++j) bv[j] = (f16)vcA[j];
            if (tt < 15) {
                const float* vp = vb + (size_t)((2 * tt + 2) * 32 + lg * 8) * D_;
                #pragma unroll
                for (int j = 0; j < 8; ++j) vcA[j] = vp[(size_t)j * D_];
            }
            acc2 = __builtin_amdgcn_mfma_f32_16x16x32_f16(pa, bv, acc2, 0, 0, 0);
        }
        // odd step t = 2*tt+1 (data in vcB)
        {
            f16x8 pa = *(const f16x8*)&S[lr * 1024 + ((((2 * tt + 1) * 4 + lg) ^ (lr & 7)) << 3)];
            f16x8 bv;
            #pragma unroll
            for (int j = 0; j < 8; ++j) bv[j] = (f16)vcB[j];
            if (tt < 15) {
                const float* vp = vb + (size_t)((2 * tt + 3) * 32 + lg * 8) * D_;
                #pragma unroll
                for (int j = 0; j < 8; ++j) vcB[j] = vp[(size_t)j * D_];
            }
            acc2 = __builtin_amdgcn_mfma_f32_16x16x32_f16(pa, bv, acc2, 0, 0, 0);
        }
    }

    // ---- epilogue: scale by 1/rowsum ----
    #pragma unroll
    for (int r2 = 0; r2 < 4; ++r2) {
        const float invr = 1.0f / wsum[lg * 4 + r2];
        out[(size_t)(qbase + lg * 4 + r2) * D_ + w * 16 + lr] = acc2[r2] * invr;
    }
}

extern "C" void kernel_launch(void* const* d_in, const int* in_sizes, int n_in,
                              void* d_out, int out_size, void* d_ws, size_t ws_size,
                              hipStream_t stream) {
    const float* q = (const float*)d_in[0];
    const float* k = (const float*)d_in[1];
    const float* v = (const float*)d_in[2];
    const unsigned char* mask = (const unsigned char*)d_in[3];
    float* out = (float*)d_out;
    float* attn = out + (size_t)B_ * L_ * D_;
    dim3 grid(B_ * (L_ / QT));
    sdpa_kernel<<<grid, 256, 0, stream>>>(q, k, v, mask, out, attn);
}